// Round 1
// baseline (2726.794 us; speedup 1.0000x reference)
//
#include <hip/hip_runtime.h>
#include <hip/hip_bf16.h>
#include <stdint.h>

// ---------------- problem constants ----------------
#define ORIGV 19986
#define NEWV  37964
#define FACT  1024
#define DIM   768
#define BATCH 4096
#define NEGK  5
#define TOTALV (ORIGV + NEWV)
#define NPAD  20096   // 157*128  (padded ORIG)
#define NTIL1 157
#define NP2   896     // 7*128    (DIM + 1 denom col + pad)
#define NTIL2 7
#define MAXSLOTS 28672  // 4096*7 worst-case unique new ids
#define SHIFTC 300.0f

typedef unsigned short u16;
typedef __attribute__((ext_vector_type(8))) short short8;
typedef __attribute__((ext_vector_type(4))) float f32x4;

__device__ __forceinline__ u16 f2bf(float f) {
  uint32_t u = __builtin_bit_cast(uint32_t, f);
  u = (u + 0x7FFFu + ((u >> 16) & 1u)) >> 16;
  return (u16)u;
}

// ---------------- prepass kernels ----------------

__global__ void k_mark(const int* __restrict__ in_ids, const int* __restrict__ pos_ids,
                       const int* __restrict__ neg_ids, int* __restrict__ rowmap) {
  int i = blockIdx.x * blockDim.x + threadIdx.x;
  int id;
  if (i < BATCH) id = in_ids[i];
  else if (i < 2 * BATCH) id = pos_ids[i - BATCH];
  else if (i < 2 * BATCH + BATCH * NEGK) id = neg_ids[i - 2 * BATCH];
  else return;
  if (id >= ORIGV) rowmap[id - ORIGV] = 1;
}

__global__ void k_compact(int* __restrict__ rowmap, int* __restrict__ list,
                          int* __restrict__ count) {
  int r = blockIdx.x * blockDim.x + threadIdx.x;
  if (r >= NEWV) return;
  if (rowmap[r]) {
    int s = atomicAdd(count, 1);
    list[s] = r;
    rowmap[r] = s + 1;
  }
}

// A_W_2 [FACT][ORIGV] f32  ->  A2t [NPAD][FACT] bf16 (zero pad rows >= ORIGV)
__global__ void k_transA2(const float* __restrict__ A2, u16* __restrict__ A2t) {
  __shared__ float tile[32][33];
  int tx = threadIdx.x & 31, ty = threadIdx.x >> 5;
  int r0 = blockIdx.x * 32;  // dst row (ORIG axis)
  int c0 = blockIdx.y * 32;  // dst col (FACT axis)
#pragma unroll
  for (int i = 0; i < 4; ++i) {
    int cc = ty + i * 8;
    int rr = r0 + tx;
    tile[cc][tx] = (rr < ORIGV) ? A2[(long)(c0 + cc) * ORIGV + rr] : 0.f;
  }
  __syncthreads();
#pragma unroll
  for (int i = 0; i < 4; ++i) {
    int r = r0 + ty + i * 8;
    A2t[(long)r * FACT + c0 + tx] = f2bf(tile[tx][ty + i * 8]);
  }
}

// W [ORIGV][DIM] f32 -> Wt [NP2][NPAD] bf16 ; row DIM = ones (denominator), rows > DIM = 0
__global__ void k_transW(const float* __restrict__ W, u16* __restrict__ Wt) {
  __shared__ float tile[32][33];
  int tx = threadIdx.x & 31, ty = threadIdx.x >> 5;
  int r0 = blockIdx.x * 32;  // dst row (DIM axis, up to NP2)
  int c0 = blockIdx.y * 32;  // dst col (ORIG axis, up to NPAD)
#pragma unroll
  for (int i = 0; i < 4; ++i) {
    int cc = ty + i * 8;
    int sc = c0 + cc;   // ORIG index
    int sr = r0 + tx;   // DIM index
    tile[cc][tx] = (sc < ORIGV && sr < DIM) ? W[(long)sc * DIM + sr] : 0.f;
  }
  __syncthreads();
#pragma unroll
  for (int i = 0; i < 4; ++i) {
    int r = r0 + ty + i * 8;
    int c = c0 + tx;
    float v;
    if (r < DIM) v = tile[tx][ty + i * 8];
    else if (r == DIM) v = (c < ORIGV) ? 1.f : 0.f;
    else v = 0.f;
    Wt[(long)r * NPAD + c] = f2bf(v);
  }
}

// gather+convert A_W_1 rows for needed slots -> A1g [MAXSLOTS][FACT] bf16 (zeros past count)
__global__ void k_gather(const float* __restrict__ A1, const int* __restrict__ list,
                         const int* __restrict__ count, u16* __restrict__ A1g) {
  int i = blockIdx.x * blockDim.x + threadIdx.x;  // over MAXSLOTS*128 8-elem chunks
  int row = i >> 7;
  int c0 = (i & 127) * 8;
  short8 v = {0, 0, 0, 0, 0, 0, 0, 0};
  if (row < *count) {
    int r = list[row];
    const float* s = A1 + (long)r * FACT + c0;
    float4 f0 = *reinterpret_cast<const float4*>(s);
    float4 f1 = *reinterpret_cast<const float4*>(s + 4);
    v[0] = (short)f2bf(f0.x); v[1] = (short)f2bf(f0.y);
    v[2] = (short)f2bf(f0.z); v[3] = (short)f2bf(f0.w);
    v[4] = (short)f2bf(f1.x); v[5] = (short)f2bf(f1.y);
    v[6] = (short)f2bf(f1.z); v[7] = (short)f2bf(f1.w);
  }
  *reinterpret_cast<short8*>(A1g + (long)row * FACT + c0) = v;
}

// ---------------- GEMM building blocks ----------------
// Stage a 128x64 bf16 tile (B^T layout: row-major, k contiguous) into LDS with
// source-side XOR swizzle so that swizzled ds_read_b128 frag reads are conflict-free.
__device__ __forceinline__ void stage_tile128x64(const u16* __restrict__ gsrc, long rowStride,
                                                 int row0, int kbase, u16* ldsTile, int t) {
#pragma unroll
  for (int i = 0; i < 4; ++i) {
    int flat = i * 256 + t;        // 16B-chunk index, 1024 total (128 rows * 8 slots)
    int row = flat >> 3;
    int slot = flat & 7;
    int srcSlot = slot ^ (row & 7);  // inverse swizzle on the global source
    const u16* g = gsrc + (long)(row0 + row) * rowStride + kbase + srcSlot * 8;
    u16* l = ldsTile + (size_t)(i * 256 + (t & ~63)) * 8;  // wave-uniform base; HW adds lane*16
    __builtin_amdgcn_global_load_lds((const __attribute__((address_space(1))) void*)g,
                                     (__attribute__((address_space(3))) void*)l, 16, 0, 0);
  }
}

__device__ __forceinline__ short8 frag_read(const u16* ldsTile, int row, int kElem) {
  uint32_t off = (uint32_t)(row * 128 + kElem * 2);
  off ^= (uint32_t)((row & 7) << 4);
  return *reinterpret_cast<const short8*>(reinterpret_cast<const char*>(ldsTile) + off);
}

// GEMM1: S = A1g[slots]x A2t^T, P = exp(S - 300) in bf16. Tile 128x128, K=1024.
__global__ __launch_bounds__(256) void k_gemm1(const u16* __restrict__ A1g,
                                               const u16* __restrict__ A2t,
                                               u16* __restrict__ P,
                                               const int* __restrict__ count, int slot0) {
  __shared__ u16 ldsA[128 * 64];
  __shared__ u16 ldsB[128 * 64];
  int t = threadIdx.x;
  int gs0 = slot0 + blockIdx.x * 128;
  if (gs0 >= *count) return;
  int n0 = blockIdx.y * 128;
  int lane = t & 63, w = t >> 6;
  int wm = w >> 1, wn = w & 1;
  int l15 = lane & 15, l4 = lane >> 4;
  f32x4 acc[4][4];
#pragma unroll
  for (int a = 0; a < 4; ++a)
#pragma unroll
    for (int b = 0; b < 4; ++b) acc[a][b] = (f32x4){0.f, 0.f, 0.f, 0.f};

  for (int kt = 0; kt < FACT / 64; ++kt) {
    int kb = kt * 64;
    stage_tile128x64(A1g, FACT, gs0, kb, ldsA, t);
    stage_tile128x64(A2t, FACT, n0, kb, ldsB, t);
    __syncthreads();
#pragma unroll
    for (int kk = 0; kk < 2; ++kk) {
      short8 af[4], bf[4];
#pragma unroll
      for (int mf = 0; mf < 4; ++mf) af[mf] = frag_read(ldsA, wm * 64 + mf * 16 + l15, kk * 32 + l4 * 8);
#pragma unroll
      for (int nf = 0; nf < 4; ++nf) bf[nf] = frag_read(ldsB, wn * 64 + nf * 16 + l15, kk * 32 + l4 * 8);
#pragma unroll
      for (int mf = 0; mf < 4; ++mf)
#pragma unroll
        for (int nf = 0; nf < 4; ++nf)
          acc[mf][nf] = __builtin_amdgcn_mfma_f32_16x16x32_bf16(af[mf], bf[nf], acc[mf][nf], 0, 0, 0);
    }
    __syncthreads();
  }
  int prow0 = blockIdx.x * 128;  // chunk-local P row
#pragma unroll
  for (int mf = 0; mf < 4; ++mf)
#pragma unroll
    for (int nf = 0; nf < 4; ++nf)
#pragma unroll
      for (int r = 0; r < 4; ++r) {
        int m = wm * 64 + mf * 16 + l4 * 4 + r;
        int n = n0 + wn * 64 + nf * 16 + l15;
        float p = __expf(acc[mf][nf][r] - SHIFTC);
        P[(long)(prow0 + m) * NPAD + n] = f2bf(p);
      }
}

// GEMM2: O = P x Wt^T (col DIM = denominator). Tile 128x128, K = NPAD.
__global__ __launch_bounds__(256) void k_gemm2(const u16* __restrict__ P,
                                               const u16* __restrict__ Wt,
                                               float* __restrict__ Obuf,
                                               const int* __restrict__ count, int slot0) {
  __shared__ u16 ldsA[128 * 64];
  __shared__ u16 ldsB[128 * 64];
  int t = threadIdx.x;
  int gs0 = slot0 + blockIdx.x * 128;
  if (gs0 >= *count) return;
  int n0 = blockIdx.y * 128;
  int lane = t & 63, w = t >> 6;
  int wm = w >> 1, wn = w & 1;
  int l15 = lane & 15, l4 = lane >> 4;
  f32x4 acc[4][4];
#pragma unroll
  for (int a = 0; a < 4; ++a)
#pragma unroll
    for (int b = 0; b < 4; ++b) acc[a][b] = (f32x4){0.f, 0.f, 0.f, 0.f};

  int prow0 = blockIdx.x * 128;
  for (int kt = 0; kt < NPAD / 64; ++kt) {
    int kb = kt * 64;
    stage_tile128x64(P, NPAD, prow0, kb, ldsA, t);
    stage_tile128x64(Wt, NPAD, n0, kb, ldsB, t);
    __syncthreads();
#pragma unroll
    for (int kk = 0; kk < 2; ++kk) {
      short8 af[4], bf[4];
#pragma unroll
      for (int mf = 0; mf < 4; ++mf) af[mf] = frag_read(ldsA, wm * 64 + mf * 16 + l15, kk * 32 + l4 * 8);
#pragma unroll
      for (int nf = 0; nf < 4; ++nf) bf[nf] = frag_read(ldsB, wn * 64 + nf * 16 + l15, kk * 32 + l4 * 8);
#pragma unroll
      for (int mf = 0; mf < 4; ++mf)
#pragma unroll
        for (int nf = 0; nf < 4; ++nf)
          acc[mf][nf] = __builtin_amdgcn_mfma_f32_16x16x32_bf16(af[mf], bf[nf], acc[mf][nf], 0, 0, 0);
    }
    __syncthreads();
  }
#pragma unroll
  for (int mf = 0; mf < 4; ++mf)
#pragma unroll
    for (int nf = 0; nf < 4; ++nf)
#pragma unroll
      for (int r = 0; r < 4; ++r) {
        int m = wm * 64 + mf * 16 + l4 * 4 + r;
        int n = n0 + wn * 64 + nf * 16 + l15;
        Obuf[(long)(gs0 + m) * NP2 + n] = acc[mf][nf][r];
      }
}

// ---------------- scoring ----------------
__global__ __launch_bounds__(256) void k_score(const float* __restrict__ W,
                                               const float* __restrict__ Obuf,
                                               const int* __restrict__ rowmap,
                                               const int* __restrict__ in_ids,
                                               const int* __restrict__ pos_ids,
                                               const int* __restrict__ neg_ids,
                                               float* __restrict__ lossAcc) {
  int t = threadIdx.x;
  int b = blockIdx.x * 4 + (t >> 6);
  int lane = t & 63;

  auto resolve = [&](int id, const float*& p, float& sc) {
    if (id < ORIGV) { p = W + (long)id * DIM; sc = 1.f; }
    else {
      int s = rowmap[id - ORIGV] - 1;
      p = Obuf + (long)s * NP2;
      sc = 1.f / p[DIM];  // softmax denominator folded into the bilinear score
    }
  };

  const float* pin; float scin;
  resolve(in_ids[b], pin, scin);
  float e[12];
#pragma unroll
  for (int j = 0; j < 12; ++j) e[j] = pin[lane + j * 64];

  auto wdot = [&](const float* q) {
    float d = 0.f;
#pragma unroll
    for (int j = 0; j < 12; ++j) d += e[j] * q[lane + j * 64];
#pragma unroll
    for (int off = 32; off > 0; off >>= 1) d += __shfl_xor(d, off);
    return d;
  };

  const float* pp; float scp;
  resolve(pos_ids[b], pp, scp);
  float ps = wdot(pp) * scin * scp;

  float sum5 = 0.f;
  for (int k = 0; k < NEGK; ++k) {
    const float* pn; float scn;
    resolve(neg_ids[b * NEGK + k], pn, scn);
    sum5 += wdot(pn) * scin * scn;
  }
  float posl = fmaxf(-ps, 0.f) + log1pf(__expf(-fabsf(ps)));
  float negl = fmaxf(sum5, 0.f) + log1pf(__expf(-fabsf(sum5)));
  if (lane == 0) atomicAdd(lossAcc, posl + negl);
}

__global__ void k_final(const float* __restrict__ lossAcc, float* __restrict__ out) {
  out[0] = lossAcc[0] * (1.f / (float)BATCH);
}

// ---------------- host launcher ----------------
extern "C" void kernel_launch(void* const* d_in, const int* in_sizes, int n_in,
                              void* d_out, int out_size, void* d_ws, size_t ws_size,
                              hipStream_t stream) {
  const float* W  = (const float*)d_in[0];
  const float* A1 = (const float*)d_in[1];
  const float* A2 = (const float*)d_in[2];
  const int* in_ids  = (const int*)d_in[3];
  const int* pos_ids = (const int*)d_in[4];
  const int* neg_ids = (const int*)d_in[5];
  float* out = (float*)d_out;

  char* ws = (char*)d_ws;
  size_t off = 0;
  auto alloc = [&](size_t bytes) -> char* {
    char* p = ws + off;
    off = (off + bytes + 255) & ~(size_t)255;
    return p;
  };
  u16*   A2t    = (u16*)alloc((size_t)NPAD * FACT * 2);       //  41.2 MB
  u16*   Wt     = (u16*)alloc((size_t)NP2 * NPAD * 2);        //  36.0 MB
  u16*   A1g    = (u16*)alloc((size_t)MAXSLOTS * FACT * 2);   //  58.7 MB
  float* Obuf   = (float*)alloc((size_t)MAXSLOTS * NP2 * 4);  // 102.8 MB
  int*   rowmap = (int*)alloc((size_t)NEWV * 4);
  int*   count  = (int*)alloc(4);
  float* lossAcc= (float*)alloc(4);
  int*   list   = (int*)alloc((size_t)MAXSLOTS * 4);
  u16*   P      = (u16*)(ws + off);                            // rest: P chunks
  size_t prem   = (ws_size > off) ? (ws_size - off) : 0;
  long chRows = (long)(prem / ((size_t)NPAD * 2));
  chRows &= ~127L;
  if (chRows <= 0) return;  // workspace too small — visible clean failure
  if (chRows > MAXSLOTS) chRows = MAXSLOTS;
  int nch = (int)((MAXSLOTS + chRows - 1) / chRows);

  hipMemsetAsync(rowmap, 0, (size_t)NEWV * 4, stream);
  hipMemsetAsync(count, 0, 4, stream);
  hipMemsetAsync(lossAcc, 0, 4, stream);

  k_mark<<<(2 * BATCH + BATCH * NEGK + 255) / 256, 256, 0, stream>>>(in_ids, pos_ids, neg_ids, rowmap);
  k_compact<<<(NEWV + 255) / 256, 256, 0, stream>>>(rowmap, list, count);
  k_transA2<<<dim3(NPAD / 32, FACT / 32), 256, 0, stream>>>(A2, A2t);
  k_transW<<<dim3(NP2 / 32, NPAD / 32), 256, 0, stream>>>(W, Wt);
  k_gather<<<(MAXSLOTS * 128) / 256, 256, 0, stream>>>(A1, list, count, A1g);

  for (int c = 0; c < nch; ++c) {
    int slot0 = c * (int)chRows;
    int rows = MAXSLOTS - slot0;
    if (rows > (int)chRows) rows = (int)chRows;
    int mb = rows / 128;
    k_gemm1<<<dim3(mb, NTIL1), 256, 0, stream>>>(A1g, A2t, P, count, slot0);
    k_gemm2<<<dim3(mb, NTIL2), 256, 0, stream>>>(P, Wt, Obuf, count, slot0);
  }

  k_score<<<BATCH / 4, 256, 0, stream>>>(W, Obuf, rowmap, in_ids, pos_ids, neg_ids, lossAcc);
  k_final<<<1, 1, 0, stream>>>(lossAcc, out);
}

// Round 2
// 2255.142 us; speedup vs baseline: 1.2091x; 1.2091x over previous
//
#include <hip/hip_runtime.h>
#include <hip/hip_bf16.h>
#include <stdint.h>

// ---------------- problem constants ----------------
#define ORIGV 19986
#define NEWV  37964
#define FACT  1024
#define DIM   768
#define BATCH 4096
#define NEGK  5
#define NPADC 20224     // 79*256 padded ORIG (k-dim of gemm2, n-dim of gemm1)
#define NT1   79        // gemm1 N tiles (256)
#define NKT1  16        // gemm1 K tiles (1024/64)
#define NKT2  316       // gemm2 K tiles (20224/64)
#define NP2B  1024      // gemm2 N (768 dims + denom at 768 + pad), 4 tiles
#define MAXSLOTS 28672  // 112*256 worst-case unique new ids
#define SHIFTC 300.0f

typedef unsigned short u16;
typedef __attribute__((ext_vector_type(8))) short short8;
typedef __attribute__((ext_vector_type(4))) float f32x4;

__device__ __forceinline__ u16 f2bf(float f) {
  uint32_t u = __builtin_bit_cast(uint32_t, f);
  u = (u + 0x7FFFu + ((u >> 16) & 1u)) >> 16;
  return (u16)u;
}

// ---------------- prepass kernels ----------------

__global__ void k_mark(const int* __restrict__ in_ids, const int* __restrict__ pos_ids,
                       const int* __restrict__ neg_ids, int* __restrict__ rowmap) {
  int i = blockIdx.x * blockDim.x + threadIdx.x;
  int id;
  if (i < BATCH) id = in_ids[i];
  else if (i < 2 * BATCH) id = pos_ids[i - BATCH];
  else if (i < 2 * BATCH + BATCH * NEGK) id = neg_ids[i - 2 * BATCH];
  else return;
  if (id >= ORIGV) rowmap[id - ORIGV] = 1;
}

__global__ void k_compact(int* __restrict__ rowmap, int* __restrict__ list,
                          int* __restrict__ count) {
  int r = blockIdx.x * blockDim.x + threadIdx.x;
  if (r >= NEWV) return;
  if (rowmap[r]) {
    int s = atomicAdd(count, 1);
    list[s] = r;
    rowmap[r] = s + 1;
  }
}

// A_W_2 [FACT][ORIGV] f32 -> A2t [NPADC][FACT] bf16 (zero pad rows >= ORIGV)
__global__ void k_transA2(const float* __restrict__ A2, u16* __restrict__ A2t) {
  __shared__ float tile[32][33];
  int tx = threadIdx.x & 31, ty = threadIdx.x >> 5;
  int r0 = blockIdx.x * 32;  // dst row (ORIG axis)
  int c0 = blockIdx.y * 32;  // dst col (FACT axis)
#pragma unroll
  for (int i = 0; i < 4; ++i) {
    int cc = ty + i * 8;
    int rr = r0 + tx;
    tile[cc][tx] = (rr < ORIGV) ? A2[(long)(c0 + cc) * ORIGV + rr] : 0.f;
  }
  __syncthreads();
#pragma unroll
  for (int i = 0; i < 4; ++i) {
    int r = r0 + ty + i * 8;
    A2t[(long)r * FACT + c0 + tx] = f2bf(tile[tx][ty + i * 8]);
  }
}

// W [ORIGV][DIM] f32 -> Wt [NP2B][NPADC] bf16 ; row DIM = ones (denominator), others pad 0
__global__ void k_transW(const float* __restrict__ W, u16* __restrict__ Wt) {
  __shared__ float tile[32][33];
  int tx = threadIdx.x & 31, ty = threadIdx.x >> 5;
  int r0 = blockIdx.x * 32;  // dst row (DIM axis, up to NP2B)
  int c0 = blockIdx.y * 32;  // dst col (ORIG axis, up to NPADC)
#pragma unroll
  for (int i = 0; i < 4; ++i) {
    int cc = ty + i * 8;
    int sc = c0 + cc;   // ORIG index
    int sr = r0 + tx;   // DIM index
    tile[cc][tx] = (sc < ORIGV && sr < DIM) ? W[(long)sc * DIM + sr] : 0.f;
  }
  __syncthreads();
#pragma unroll
  for (int i = 0; i < 4; ++i) {
    int r = r0 + ty + i * 8;
    int c = c0 + tx;
    float v;
    if (r < DIM) v = tile[tx][ty + i * 8];
    else if (r == DIM) v = (c < ORIGV) ? 1.f : 0.f;
    else v = 0.f;
    Wt[(long)r * NPADC + c] = f2bf(v);
  }
}

// gather+convert A_W_1 rows for needed slots -> A1g [MAXSLOTS][FACT] bf16 (zeros past count)
__global__ void k_gather(const float* __restrict__ A1, const int* __restrict__ list,
                         const int* __restrict__ count, u16* __restrict__ A1g) {
  int i = blockIdx.x * blockDim.x + threadIdx.x;
  int row = i >> 7;
  int c0 = (i & 127) * 8;
  short8 v = {0, 0, 0, 0, 0, 0, 0, 0};
  if (row < *count) {
    int r = list[row];
    const float* s = A1 + (long)r * FACT + c0;
    float4 f0 = *reinterpret_cast<const float4*>(s);
    float4 f1 = *reinterpret_cast<const float4*>(s + 4);
    v[0] = (short)f2bf(f0.x); v[1] = (short)f2bf(f0.y);
    v[2] = (short)f2bf(f0.z); v[3] = (short)f2bf(f0.w);
    v[4] = (short)f2bf(f1.x); v[5] = (short)f2bf(f1.y);
    v[6] = (short)f2bf(f1.z); v[7] = (short)f2bf(f1.w);
  }
  *reinterpret_cast<short8*>(A1g + (long)row * FACT + c0) = v;
}

// ---------------- GEMM building blocks (512 threads, 8 waves 2Mx4N, 256^2 tile, BK=64) ----------------
// LDS: 2 dbuf x {A,B} x 2 halves x (128 rows x 64 k) bf16 = 128 KiB.
// Half-tile = 16 KiB = 1024 x 16B chunks; 512 threads x 2 loads.
// Flat-source staging applies inverse XOR swizzle (slot ^= row&7) so swizzled
// ds_read_b128 frag reads are bank-conflict-free (round-1: 0 conflicts measured).

__device__ __forceinline__ void stage_half_flat(const u16* gRow0, long pitch, u16* ldsHalf, int t) {
#pragma unroll
  for (int i = 0; i < 2; ++i) {
    int flat = i * 512 + t;
    int row = flat >> 3;
    int slot = (flat & 7) ^ (row & 7);
    const u16* g = gRow0 + (long)row * pitch + slot * 8;
    u16* l = ldsHalf + (size_t)(flat & ~63) * 8;  // wave-uniform base; HW adds lane*16B
    __builtin_amdgcn_global_load_lds((const __attribute__((address_space(1))) void*)g,
                                     (__attribute__((address_space(3))) void*)l, 16, 0, 0);
  }
}

// P tiles already stored swizzled -> pure linear 16KB copy
__device__ __forceinline__ void stage_half_lin(const u16* gBase, u16* ldsHalf, int t) {
#pragma unroll
  for (int i = 0; i < 2; ++i) {
    int flat = i * 512 + t;
    const u16* g = gBase + (size_t)flat * 8;
    u16* l = ldsHalf + (size_t)(flat & ~63) * 8;
    __builtin_amdgcn_global_load_lds((const __attribute__((address_space(1))) void*)g,
                                     (__attribute__((address_space(3))) void*)l, 16, 0, 0);
  }
}

__device__ __forceinline__ short8 frag_read(const u16* ldsHalf, int row, int kElem) {
  uint32_t off = (uint32_t)(row * 128 + kElem * 2);
  off ^= (uint32_t)((row & 7) << 4);
  return *reinterpret_cast<const short8*>(reinterpret_cast<const char*>(ldsHalf) + off);
}

#define LDSA(b, h) (lds + (((b) * 2 + 0) * 2 + (h)) * 8192)
#define LDSB(b, h) (lds + (((b) * 2 + 1) * 2 + (h)) * 8192)

// GEMM1: S = A1g x A2t^T, P-tiles = exp(S-300) bf16 stored swizzled-tiled.
__global__ __launch_bounds__(512, 2) void k_gemm1(const u16* __restrict__ A1g,
                                                  const u16* __restrict__ A2t,
                                                  u16* __restrict__ Pt,
                                                  const int* __restrict__ count, int slot0) {
  __shared__ __align__(16) u16 lds[65536];
  int t = threadIdx.x;
  int gs0 = slot0 + blockIdx.x * 256;
  if (gs0 >= *count) return;
  int n0 = blockIdx.y * 256;
  int lane = t & 63, w = t >> 6;
  int wm = w >> 2, wn = w & 3;       // 2M x 4N; wave tile 128x64
  int l15 = lane & 15, l4 = lane >> 4;
  f32x4 acc[8][4];
#pragma unroll
  for (int a = 0; a < 8; ++a)
#pragma unroll
    for (int b = 0; b < 4; ++b) acc[a][b] = (f32x4){0.f, 0.f, 0.f, 0.f};

  // prologue: stage K-tile 0 into buf0
  stage_half_flat(A1g + (long)gs0 * FACT,          FACT, LDSA(0, 0), t);
  stage_half_flat(A1g + (long)(gs0 + 128) * FACT,  FACT, LDSA(0, 1), t);
  stage_half_flat(A2t + (long)n0 * FACT,           FACT, LDSB(0, 0), t);
  stage_half_flat(A2t + (long)(n0 + 128) * FACT,   FACT, LDSB(0, 1), t);

  for (int kt = 0; kt < NKT1; ++kt) {
    int rb = kt & 1;
    asm volatile("s_waitcnt vmcnt(0)" ::: "memory");  // own stage-loads for tile kt landed
    __builtin_amdgcn_s_barrier();                     // everyone's landed
    int ktn = (kt + 1 < NKT1) ? kt + 1 : 0;           // wrap prefetch (harmless re-stage)
    int kb = ktn * 64;
    const u16* Ah = LDSA(rb, wm);
    const u16* Bh = LDSB(rb, wn >> 1);
    int brow0 = (wn & 1) * 64;
#pragma unroll
    for (int q = 0; q < 4; ++q) {
      const int mq = q & 1, nq = q >> 1;
      short8 af[4][2], bfr[2][2];
#pragma unroll
      for (int ks = 0; ks < 2; ++ks) {
#pragma unroll
        for (int mf = 0; mf < 4; ++mf)
          af[mf][ks] = frag_read(Ah, (mq * 4 + mf) * 16 + l15, ks * 32 + l4 * 8);
#pragma unroll
        for (int nf = 0; nf < 2; ++nf)
          bfr[nf][ks] = frag_read(Bh, brow0 + (nq * 2 + nf) * 16 + l15, ks * 32 + l4 * 8);
      }
      if (q == 0) {   // prefetch next tile's A halves (~3 phases of cover)
        stage_half_flat(A1g + (long)gs0 * FACT + kb,         FACT, LDSA(rb ^ 1, 0), t);
        stage_half_flat(A1g + (long)(gs0 + 128) * FACT + kb, FACT, LDSA(rb ^ 1, 1), t);
      } else if (q == 1) {  // B halves (~2.5 phases of cover)
        stage_half_flat(A2t + (long)n0 * FACT + kb,          FACT, LDSB(rb ^ 1, 0), t);
        stage_half_flat(A2t + (long)(n0 + 128) * FACT + kb,  FACT, LDSB(rb ^ 1, 1), t);
      }
      __builtin_amdgcn_sched_barrier(0);
      __builtin_amdgcn_s_setprio(1);
#pragma unroll
      for (int mf = 0; mf < 4; ++mf)
#pragma unroll
        for (int nf = 0; nf < 2; ++nf)
#pragma unroll
          for (int ks = 0; ks < 2; ++ks)
            acc[mq * 4 + mf][nq * 2 + nf] = __builtin_amdgcn_mfma_f32_16x16x32_bf16(
                af[mf][ks], bfr[nf][ks], acc[mq * 4 + mf][nq * 2 + nf], 0, 0, 0);
      __builtin_amdgcn_s_setprio(0);
      __builtin_amdgcn_sched_barrier(0);
      __builtin_amdgcn_s_barrier();
    }
  }

  // epilogue: exp + write P tiles (chunk-local tiled layout, swizzle baked in)
  int mloc0 = blockIdx.x * 256 + wm * 128;
#pragma unroll
  for (int mi = 0; mi < 8; ++mi)
#pragma unroll
    for (int ni = 0; ni < 4; ++ni)
#pragma unroll
      for (int r = 0; r < 4; ++r) {
        int mrow = mloc0 + mi * 16 + l4 * 4 + r;
        int kcol = n0 + wn * 64 + ni * 16 + l15;
        int mb2 = mrow >> 7, mr = mrow & 127;
        int kb2 = kcol >> 6, kr = kcol & 63;
        size_t tbase = ((size_t)mb2 * NKT2 + kb2) * 8192;  // elems
        uint32_t boff = ((uint32_t)(mr * 128 + kr * 2)) ^ (uint32_t)((mr & 7) << 4);
        float p = __expf(acc[mi][ni][r] - SHIFTC);
        *(u16*)((char*)Pt + tbase * 2 + boff) = f2bf(p);
      }
}

// GEMM2: O = P x Wt^T (col DIM=768 is the softmax denominator). K = NPADC.
__global__ __launch_bounds__(512, 2) void k_gemm2(const u16* __restrict__ Pt,
                                                  const u16* __restrict__ Wt,
                                                  float* __restrict__ Obuf,
                                                  const int* __restrict__ count, int slot0) {
  __shared__ __align__(16) u16 lds[65536];
  int t = threadIdx.x;
  int gs0 = slot0 + blockIdx.x * 256;
  if (gs0 >= *count) return;
  int n0 = blockIdx.y * 256;
  int lane = t & 63, w = t >> 6;
  int wm = w >> 2, wn = w & 3;
  int l15 = lane & 15, l4 = lane >> 4;
  f32x4 acc[8][4];
#pragma unroll
  for (int a = 0; a < 8; ++a)
#pragma unroll
    for (int b = 0; b < 4; ++b) acc[a][b] = (f32x4){0.f, 0.f, 0.f, 0.f};

  size_t mb2a = (size_t)blockIdx.x * 2;  // chunk-local tile rows
  // prologue: stage K-tile 0
  stage_half_lin(Pt + (mb2a * NKT2 + 0) * 8192,       LDSA(0, 0), t);
  stage_half_lin(Pt + ((mb2a + 1) * NKT2 + 0) * 8192, LDSA(0, 1), t);
  stage_half_flat(Wt + (long)n0 * NPADC,              NPADC, LDSB(0, 0), t);
  stage_half_flat(Wt + (long)(n0 + 128) * NPADC,      NPADC, LDSB(0, 1), t);

  for (int kt = 0; kt < NKT2; ++kt) {
    int rb = kt & 1;
    asm volatile("s_waitcnt vmcnt(0)" ::: "memory");
    __builtin_amdgcn_s_barrier();
    int ktn = (kt + 1 < NKT2) ? kt + 1 : 0;
    int kb = ktn * 64;
    const u16* Ah = LDSA(rb, wm);
    const u16* Bh = LDSB(rb, wn >> 1);
    int brow0 = (wn & 1) * 64;
#pragma unroll
    for (int q = 0; q < 4; ++q) {
      const int mq = q & 1, nq = q >> 1;
      short8 af[4][2], bfr[2][2];
#pragma unroll
      for (int ks = 0; ks < 2; ++ks) {
#pragma unroll
        for (int mf = 0; mf < 4; ++mf)
          af[mf][ks] = frag_read(Ah, (mq * 4 + mf) * 16 + l15, ks * 32 + l4 * 8);
#pragma unroll
        for (int nf = 0; nf < 2; ++nf)
          bfr[nf][ks] = frag_read(Bh, brow0 + (nq * 2 + nf) * 16 + l15, ks * 32 + l4 * 8);
      }
      if (q == 0) {
        stage_half_lin(Pt + (mb2a * NKT2 + ktn) * 8192,       LDSA(rb ^ 1, 0), t);
        stage_half_lin(Pt + ((mb2a + 1) * NKT2 + ktn) * 8192, LDSA(rb ^ 1, 1), t);
      } else if (q == 1) {
        stage_half_flat(Wt + (long)n0 * NPADC + kb,          NPADC, LDSB(rb ^ 1, 0), t);
        stage_half_flat(Wt + (long)(n0 + 128) * NPADC + kb,  NPADC, LDSB(rb ^ 1, 1), t);
      }
      __builtin_amdgcn_sched_barrier(0);
      __builtin_amdgcn_s_setprio(1);
#pragma unroll
      for (int mf = 0; mf < 4; ++mf)
#pragma unroll
        for (int nf = 0; nf < 2; ++nf)
#pragma unroll
          for (int ks = 0; ks < 2; ++ks)
            acc[mq * 4 + mf][nq * 2 + nf] = __builtin_amdgcn_mfma_f32_16x16x32_bf16(
                af[mf][ks], bfr[nf][ks], acc[mq * 4 + mf][nq * 2 + nf], 0, 0, 0);
      __builtin_amdgcn_s_setprio(0);
      __builtin_amdgcn_sched_barrier(0);
      __builtin_amdgcn_s_barrier();
    }
  }

#pragma unroll
  for (int mi = 0; mi < 8; ++mi)
#pragma unroll
    for (int ni = 0; ni < 4; ++ni)
#pragma unroll
      for (int r = 0; r < 4; ++r) {
        int m = gs0 + wm * 128 + mi * 16 + l4 * 4 + r;
        int n = n0 + wn * 64 + ni * 16 + l15;
        Obuf[(size_t)m * NP2B + n] = acc[mi][ni][r];
      }
}

// ---------------- scoring ----------------
__global__ __launch_bounds__(256) void k_score(const float* __restrict__ W,
                                               const float* __restrict__ Obuf,
                                               const int* __restrict__ rowmap,
                                               const int* __restrict__ in_ids,
                                               const int* __restrict__ pos_ids,
                                               const int* __restrict__ neg_ids,
                                               float* __restrict__ lossAcc) {
  int t = threadIdx.x;
  int b = blockIdx.x * 4 + (t >> 6);
  int lane = t & 63;

  auto resolve = [&](int id, const float*& p, float& sc) {
    if (id < ORIGV) { p = W + (long)id * DIM; sc = 1.f; }
    else {
      int s = rowmap[id - ORIGV] - 1;
      p = Obuf + (size_t)s * NP2B;
      sc = 1.f / p[DIM];  // softmax denominator folded into the bilinear score
    }
  };

  const float* pin; float scin;
  resolve(in_ids[b], pin, scin);
  float e[12];
#pragma unroll
  for (int j = 0; j < 12; ++j) e[j] = pin[lane + j * 64];

  auto wdot = [&](const float* q) {
    float d = 0.f;
#pragma unroll
    for (int j = 0; j < 12; ++j) d += e[j] * q[lane + j * 64];
#pragma unroll
    for (int off = 32; off > 0; off >>= 1) d += __shfl_xor(d, off);
    return d;
  };

  const float* pp; float scp;
  resolve(pos_ids[b], pp, scp);
  float ps = wdot(pp) * scin * scp;

  float sum5 = 0.f;
  for (int k = 0; k < NEGK; ++k) {
    const float* pn; float scn;
    resolve(neg_ids[b * NEGK + k], pn, scn);
    sum5 += wdot(pn) * scin * scn;
  }
  float posl = fmaxf(-ps, 0.f) + log1pf(__expf(-fabsf(ps)));
  float negl = fmaxf(sum5, 0.f) + log1pf(__expf(-fabsf(sum5)));
  if (lane == 0) atomicAdd(lossAcc, posl + negl);
}

__global__ void k_final(const float* __restrict__ lossAcc, float* __restrict__ out) {
  out[0] = lossAcc[0] * (1.f / (float)BATCH);
}

// ---------------- host launcher ----------------
extern "C" void kernel_launch(void* const* d_in, const int* in_sizes, int n_in,
                              void* d_out, int out_size, void* d_ws, size_t ws_size,
                              hipStream_t stream) {
  const float* W  = (const float*)d_in[0];
  const float* A1 = (const float*)d_in[1];
  const float* A2 = (const float*)d_in[2];
  const int* in_ids  = (const int*)d_in[3];
  const int* pos_ids = (const int*)d_in[4];
  const int* neg_ids = (const int*)d_in[5];
  float* out = (float*)d_out;

  char* ws = (char*)d_ws;
  size_t off = 0;
  auto alloc = [&](size_t bytes) -> char* {
    char* p = ws + off;
    off = (off + bytes + 255) & ~(size_t)255;
    return p;
  };
  u16*   A2t    = (u16*)alloc((size_t)NPADC * FACT * 2);       //  41.4 MB
  u16*   Wt     = (u16*)alloc((size_t)NP2B * NPADC * 2);       //  41.4 MB
  u16*   A1g    = (u16*)alloc((size_t)MAXSLOTS * FACT * 2);    //  58.7 MB
  float* Obuf   = (float*)alloc((size_t)MAXSLOTS * NP2B * 4);  // 117.4 MB
  int*   rowmap = (int*)alloc((size_t)NEWV * 4);
  int*   count  = (int*)alloc(4);
  float* lossAcc= (float*)alloc(4);
  int*   list   = (int*)alloc((size_t)MAXSLOTS * 4);
  u16*   P      = (u16*)(ws + off);                            // rest: tiled P chunks
  size_t prem   = (ws_size > off) ? (ws_size - off) : 0;
  long chRows = (long)(prem / ((size_t)NPADC * 2));
  chRows &= ~255L;
  if (chRows <= 0) return;  // workspace too small — visible clean failure
  if (chRows > MAXSLOTS) chRows = MAXSLOTS;
  int nch = (int)((MAXSLOTS + chRows - 1) / chRows);

  hipMemsetAsync(rowmap, 0, (size_t)NEWV * 4, stream);
  hipMemsetAsync(count, 0, 4, stream);
  hipMemsetAsync(lossAcc, 0, 4, stream);

  k_mark<<<(2 * BATCH + BATCH * NEGK + 255) / 256, 256, 0, stream>>>(in_ids, pos_ids, neg_ids, rowmap);
  k_compact<<<(NEWV + 255) / 256, 256, 0, stream>>>(rowmap, list, count);
  k_transA2<<<dim3(NPADC / 32, FACT / 32), 256, 0, stream>>>(A2, A2t);
  k_transW<<<dim3(NP2B / 32, NPADC / 32), 256, 0, stream>>>(W, Wt);
  k_gather<<<(MAXSLOTS * 128) / 256, 256, 0, stream>>>(A1, list, count, A1g);

  for (int c = 0; c < nch; ++c) {
    int slot0 = c * (int)chRows;
    int rows = MAXSLOTS - slot0;
    if (rows > (int)chRows) rows = (int)chRows;
    int mb = rows / 256;
    k_gemm1<<<dim3(mb, NT1), 512, 0, stream>>>(A1g, A2t, P, count, slot0);
    k_gemm2<<<dim3(mb, NP2B / 256), 512, 0, stream>>>(P, Wt, Obuf, count, slot0);
  }

  k_score<<<BATCH / 4, 256, 0, stream>>>(W, Obuf, rowmap, in_ids, pos_ids, neg_ids, lossAcc);
  k_final<<<1, 1, 0, stream>>>(lossAcc, out);
}